// Round 12
// baseline (190.276 us; speedup 1.0000x reference)
//
#include <hip/hip_runtime.h>

// Problem constants
#define BB 2
#define TT 2048
#define CC 1024
#define NH 16
#define HD 64

typedef __attribute__((ext_vector_type(8))) short bf16x8;
typedef __attribute__((ext_vector_type(4))) float floatx4;
typedef __attribute__((ext_vector_type(16))) float floatx16;

__device__ __forceinline__ unsigned short f2bf(float f) {
    union { float f; unsigned int u; } v; v.f = f;
    unsigned int u = v.u;
    u = (u + 0x7fffu + ((u >> 16) & 1u)) >> 16;   // RNE
    return (unsigned short)u;
}
__device__ __forceinline__ float bf2f(unsigned short u) {
    return __uint_as_float((unsigned)u << 16);
}

typedef __attribute__((address_space(3))) unsigned char* lds_ptr_t;
typedef const __attribute__((address_space(1))) unsigned char* glob_ptr_t;
__device__ __forceinline__ void gll16(const void* g, void* l) {
    __builtin_amdgcn_global_load_lds((glob_ptr_t)g, (lds_ptr_t)l, 16, 0, 0);
}

// ---------------- fused cast fp32 -> bf16 + RoPE table build ----------------
__global__ __launch_bounds__(256) void cast_all_k(const float* __restrict__ x,
                                                  const float* __restrict__ wq,
                                                  const float* __restrict__ wk,
                                                  const float* __restrict__ wv,
                                                  const float* __restrict__ wo,
                                                  unsigned short* __restrict__ xb,
                                                  unsigned short* __restrict__ wqkvb,
                                                  unsigned short* __restrict__ wob,
                                                  float2* __restrict__ tabQ,
                                                  float2* __restrict__ tabK) {
    if (blockIdx.x >= 8192) {   // RoPE tables: 2048 t x 32 pairs
        int idx = (blockIdx.x - 8192) * 256 + threadIdx.x;   // 0..65535
        int t = idx >> 5, j = idx & 31;
        const float C1 = 0.41524101186092f;        // log2(10000)/32
        const float I2PI = 0.15915494309189535f;
        float rev = (float)t * (__builtin_amdgcn_exp2f(-(float)j * C1) * I2PI);
        rev -= floorf(rev);
        float ang = rev * 6.2831853071796f;
        float c = __cosf(ang), s = __sinf(ang);
        const float qs = 0.18033688011112f;        // (1/8)*log2(e), folded into Q table
        tabK[idx] = make_float2(c, s);
        tabQ[idx] = make_float2(c * qs, s * qs);
        return;
    }
    int i = blockIdx.x * 256 + threadIdx.x;   // float4 index
    const float* src;
    unsigned short* dst;
    if (i < 1048576) {
        src = x + (size_t)i * 4;
        dst = xb + (size_t)i * 4;
    } else {
        int w   = (i - 1048576) >> 18;        // 0..3
        int off = (i - 1048576) & 262143;
        const float* s0 = (w == 0) ? wq : (w == 1) ? wk : (w == 2) ? wv : wo;
        unsigned short* d0 = (w == 3) ? wob : (wqkvb + (size_t)w * 1048576);
        src = s0 + (size_t)off * 4;
        dst = d0 + (size_t)off * 4;
    }
    float4 v = *(const float4*)src;
    ushort4 o;
    o.x = f2bf(v.x); o.y = f2bf(v.y); o.z = f2bf(v.z); o.w = f2bf(v.w);
    *(ushort4*)dst = o;
}

// ---------------- out-proj GEMM: 128x64 tile, BK=64, XOR-swizzled LDS, grid 512 (2 blk/CU) ----------------
__global__ __launch_bounds__(256, 2) void gemm_o_k(const unsigned short* __restrict__ A,
                                                   const unsigned short* __restrict__ Bt,
                                                   float* __restrict__ C, int N, int K) {
    __shared__ __align__(16) unsigned short As[128][64];
    __shared__ __align__(16) unsigned short Bs[64][64];
    const int tid  = threadIdx.x;
    const int wave = tid >> 6;
    const int lane = tid & 63;
    const int quad = lane >> 4;
    const int l16  = lane & 15;
    const int sw   = l16 & 7;             // fragment-read XOR key
    const int wr = (wave >> 1) * 64;      // wave row offset within 128
    const int wc = (wave & 1) * 32;       // wave col offset within 64
    const int bid = blockIdx.x;
    const int xcd = bid & 7, sl = bid >> 3;          // sl 0..63
    const int row0 = (xcd * 4 + (sl >> 4)) * 128;    // 32 row tiles
    const int col0 = (sl & 15) * 64;                 // 16 col tiles
    const int w8r = wave * 8 + (lane >> 3);
    const int cg  = ((lane & 7) ^ (lane >> 3)) * 8;  // global col (shorts), pre-swizzled
    const int cl  = (lane & 7) * 8;                  // phys LDS col (shorts)

    const unsigned short* Ap = A  + (size_t)(row0 + w8r) * K + cg;
    const unsigned short* Bp = Bt + (size_t)(col0 + w8r) * K + cg;

    floatx4 acc[4][2];
    #pragma unroll
    for (int i = 0; i < 4; i++)
        #pragma unroll
        for (int j = 0; j < 2; j++) acc[i][j] = (floatx4){0.f, 0.f, 0.f, 0.f};

    for (int k0 = 0; k0 < K; k0 += 64) {
        __syncthreads();
        #pragma unroll
        for (int isu = 0; isu < 4; isu++)
            gll16(Ap + (size_t)(isu * 32) * K + k0, &As[isu * 32 + w8r][cl]);
        #pragma unroll
        for (int isu = 0; isu < 2; isu++)
            gll16(Bp + (size_t)(isu * 32) * K + k0, &Bs[isu * 32 + w8r][cl]);
        __syncthreads();
        #pragma unroll
        for (int kk = 0; kk < 2; kk++) {
            bf16x8 af[4], bfr[2];
            #pragma unroll
            for (int i = 0; i < 4; i++)
                af[i]  = *(const bf16x8*)&As[wr + 16 * i + l16][((kk * 4 + quad) ^ sw) * 8];
            #pragma unroll
            for (int j = 0; j < 2; j++)
                bfr[j] = *(const bf16x8*)&Bs[wc + 16 * j + l16][((kk * 4 + quad) ^ sw) * 8];
            #pragma unroll
            for (int i = 0; i < 4; i++)
                #pragma unroll
                for (int j = 0; j < 2; j++)
                    acc[i][j] = __builtin_amdgcn_mfma_f32_16x16x32_bf16(af[i], bfr[j], acc[i][j], 0, 0, 0);
        }
    }

    #pragma unroll
    for (int i = 0; i < 4; i++)
        #pragma unroll
        for (int j = 0; j < 2; j++)
            #pragma unroll
            for (int r = 0; r < 4; r++) {
                int row = row0 + wr + 16 * i + quad * 4 + r;
                int col = col0 + wc + 16 * j + l16;
                C[(size_t)row * N + col] = acc[i][j][r];
            }
}

// ---------------- QKV GEMM: BK=64, XOR-swizzled LDS, table-RoPE epilogue ----------------
// V section: DIRECT acc->Vt stores with sigma slot-permutation folded into the t-base
// (no LDS bounce; vtr kernel and Vb round-trip eliminated).
// sigma: row%16 = 4q+r  ->  slot = r + 8*(q&1) + 4*(q>>1); r stays low bits, so each
// lane's 4 acc values are 4 consecutive Vt t-slots -> one ushort4 store.
__global__ __launch_bounds__(256) void gemm_qkv_k(const unsigned short* __restrict__ A,
                                                  const unsigned short* __restrict__ Bt,
                                                  const float2* __restrict__ tabQ,
                                                  const float2* __restrict__ tabK,
                                                  unsigned short* __restrict__ Qb,
                                                  unsigned short* __restrict__ Kb,
                                                  unsigned short* __restrict__ Vt) {
    __shared__ __align__(16) unsigned short SMEM[128 * 128];   // 32 KB: As+Bs in loop, Eb in epilogue
    unsigned short (*As)[64] = (unsigned short(*)[64])SMEM;
    unsigned short (*Bs)[64] = (unsigned short(*)[64])(SMEM + 128 * 64);
    unsigned short (*Eb)[128] = (unsigned short(*)[128])SMEM;
    const int K = 1024;
    const int tid  = threadIdx.x;
    const int wave = tid >> 6;
    const int lane = tid & 63;
    const int quad = lane >> 4;
    const int l16  = lane & 15;
    const int sw   = l16 & 7;
    const int wr = (wave >> 1) * 64;
    const int wc = (wave & 1) * 64;
    const int bid = blockIdx.x;
    const int xcd = bid & 7, sl = bid >> 3;          // sl 0..95
    const int row0 = (xcd * 4 + sl / 24) * 128;
    const int col0 = (sl % 24) * 128;
    const int w8r = wave * 8 + (lane >> 3);
    const int cg  = ((lane & 7) ^ (lane >> 3)) * 8;
    const int cl  = (lane & 7) * 8;

    const unsigned short* Ap = A  + (size_t)(row0 + w8r) * K + cg;
    const unsigned short* Bp = Bt + (size_t)(col0 + w8r) * K + cg;

    floatx4 acc[4][4];
    #pragma unroll
    for (int i = 0; i < 4; i++)
        #pragma unroll
        for (int j = 0; j < 4; j++) acc[i][j] = (floatx4){0.f, 0.f, 0.f, 0.f};

    for (int k0 = 0; k0 < K; k0 += 64) {
        __syncthreads();
        #pragma unroll
        for (int isu = 0; isu < 4; isu++) {
            gll16(Ap + (size_t)(isu * 32) * K + k0, &As[isu * 32 + w8r][cl]);
            gll16(Bp + (size_t)(isu * 32) * K + k0, &Bs[isu * 32 + w8r][cl]);
        }
        __syncthreads();
        #pragma unroll
        for (int kk = 0; kk < 2; kk++) {
            bf16x8 af[4], bfr[4];
            #pragma unroll
            for (int i = 0; i < 4; i++)
                af[i]  = *(const bf16x8*)&As[wr + 16 * i + l16][((kk * 4 + quad) ^ sw) * 8];
            #pragma unroll
            for (int j = 0; j < 4; j++)
                bfr[j] = *(const bf16x8*)&Bs[wc + 16 * j + l16][((kk * 4 + quad) ^ sw) * 8];
            #pragma unroll
            for (int i = 0; i < 4; i++)
                #pragma unroll
                for (int j = 0; j < 4; j++)
                    acc[i][j] = __builtin_amdgcn_mfma_f32_16x16x32_bf16(af[i], bfr[j], acc[i][j], 0, 0, 0);
        }
    }

    const int sect = col0 >> 10;                        // 0=Q,1=K,2=V
    if (sect == 2) {
        // ---- V: direct acc -> Vt [BH,D,T], sigma folded, no LDS bounce ----
        const int bb = row0 >> 11;
        const int hb = (col0 & 1023) >> 6;
        const int t0 = (row0 & (TT - 1)) + wr + (quad & 1) * 8 + (quad >> 1) * 4;
        #pragma unroll
        for (int jj = 0; jj < 4; jj++) {
            int dcol = wc + 16 * jj + l16;
            int bh2  = bb * NH + hb + (dcol >> 6);
            int d    = dcol & 63;
            unsigned short* vd = Vt + ((size_t)bh2 * 64 + d) * TT + t0;
            #pragma unroll
            for (int ii = 0; ii < 4; ii++) {
                ushort4 o4;
                o4.x = f2bf(acc[ii][jj][0]);
                o4.y = f2bf(acc[ii][jj][1]);
                o4.z = f2bf(acc[ii][jj][2]);
                o4.w = f2bf(acc[ii][jj][3]);
                *(ushort4*)(vd + 16 * ii) = o4;
            }
        }
    } else {
        // ---- Phase 1: acc -> Eb (bf16), XOR-granule swizzle ----
        __syncthreads();
        #pragma unroll
        for (int i = 0; i < 4; i++)
            #pragma unroll
            for (int j = 0; j < 4; j++)
                #pragma unroll
                for (int r = 0; r < 4; r++) {
                    int erow = wr + 16 * i + quad * 4 + r;
                    int col  = wc + 16 * j + l16;
                    int pcol = (((col >> 3) ^ (erow & 15)) << 3) | (col & 7);
                    Eb[erow][pcol] = f2bf(acc[i][j][r]);
                }
        __syncthreads();

        // ---- Phase 2 (Q/K): row-wise readback, RoPE via table, coalesced stores ----
        const int row  = tid >> 1;            // 0..127
        const int half = tid & 1;
        const int grow = row0 + row;
        const int t    = grow & (TT - 1);
        const int bb   = grow >> 11;
        const int hh   = ((col0 & 1023) >> 6) + half;       // head
        union { int4 q[8]; unsigned short u[64]; } raw;
        #pragma unroll
        for (int i = 0; i < 8; i++) {
            int pg = (half * 8 + i) ^ (row & 15);
            raw.q[i] = *(const int4*)&Eb[row][pg << 3];
        }
        size_t obase = ((size_t)(bb * NH + hh) * TT + t) * 64;
        const float4* tab = (const float4*)((sect ? tabK : tabQ) + (size_t)t * 32);
        unsigned short* dst = sect ? Kb : Qb;
        union { int4 q[8]; unsigned short u[64]; } o;
        #pragma unroll
        for (int i = 0; i < 16; i++) {
            float4 cs = tab[i];      // {c0,s0,c1,s1} for pairs j=2i, 2i+1
            int j0 = 2 * i, j1 = 2 * i + 1;
            float a0 = bf2f(raw.u[j0]), b0 = bf2f(raw.u[j0 + 32]);
            float a1 = bf2f(raw.u[j1]), b1 = bf2f(raw.u[j1 + 32]);
            o.u[j0]      = f2bf(a0 * cs.x - b0 * cs.y);
            o.u[j0 + 32] = f2bf(b0 * cs.x + a0 * cs.y);
            o.u[j1]      = f2bf(a1 * cs.z - b1 * cs.w);
            o.u[j1 + 32] = f2bf(b1 * cs.z + a1 * cs.w);
        }
        #pragma unroll
        for (int i = 0; i < 8; i++) *(int4*)(dst + obase + 8 * i) = o.q[i];
    }
}

// ---------------- flash attention: intra-block key-split, gll16-direct staging ----------------
// R10-proven: split-wait staging (T4-lite). Issue K-loads then V-loads; wait only the K
// portion (counted vmcnt) before QK^T; V loads land under QK+softmax; vmcnt(0)
// + barrier before PV.
__global__ __launch_bounds__(256, 4) void flash_k(const unsigned short* __restrict__ Qb,
                                                  const unsigned short* __restrict__ Kb,
                                                  const unsigned short* __restrict__ Vt,
                                                  unsigned short* __restrict__ Yb) {
    __shared__ __align__(16) unsigned short SMEM[2][2][64][64];   // [K/V][split][row][col] 32 KB
    const int tid  = threadIdx.x;
    const int wave = tid >> 6;
    const int lane = tid & 63;
    const int h    = lane >> 5;
    const int l32  = lane & 31;
    const int g    = wave >> 1;                 // q-row group 0/1
    const int s    = wave & 1;                  // key split 0/1
    const int j    = blockIdx.x >> 5;           // 0..31
    const int qj   = (j < 16) ? (31 - j) : (j - 16);
    const int bh   = blockIdx.x & 31;
    const int q0   = qj * 64;
    const int qw   = q0 + g * 32 + l32;         // this lane's q row
    const int nt   = qj + 1;                    // causal key tiles
    const int n0   = (nt + 1) >> 1;             // split0 tiles (= loop count)
    const int n1   = nt - n0;                   // split1 tiles (n0-1 or n0)
    // staging decomposition: lane -> row l8, granule lg; source granule pre-swizzled
    const int l8  = lane >> 3;                  // 0..7
    const int lg  = lane & 7;                   // dst granule (16B)
    const int srow = wave * 8 + l8;             // 0..31 (call c adds 32*c)
    const int sgr  = lg ^ l8;                   // swizzled source granule
    const int xr   = l32 & 7;                   // fragment-read XOR key

    bf16x8 qf[4];
    {
        const unsigned short* qp = Qb + ((size_t)bh * TT + qw) * 64 + h * 8;
        #pragma unroll
        for (int kk = 0; kk < 4; kk++) qf[kk] = *(const bf16x8*)(qp + kk * 16);
    }

    floatx16 accO[2];
    accO[0] = (floatx16)(0.f);
    accO[1] = (floatx16)(0.f);
    float lsum = 0.f;

    const unsigned short* kbase = Kb + (size_t)bh * TT * 64;
    const unsigned short* vbase = Vt + (size_t)bh * 64 * TT;

    for (int i = 0; i < n0; i++) {
        __syncthreads();                         // prev tile reads complete (vmcnt already 0)
        const bool both = (i < n1);
        // ---- issue K loads first (both splits), then V loads ----
        #pragma unroll
        for (int c = 0; c < 2; c++) {
            int r = 32 * c + srow;
            gll16(kbase + ((size_t)(i * 64) + r) * 64 + sgr * 8, &SMEM[0][0][r][lg * 8]);
        }
        if (both) {
            #pragma unroll
            for (int c = 0; c < 2; c++) {
                int r = 32 * c + srow;
                gll16(kbase + ((size_t)((n0 + i) * 64) + r) * 64 + sgr * 8, &SMEM[0][1][r][lg * 8]);
            }
        }
        #pragma unroll
        for (int c = 0; c < 2; c++) {
            int r = 32 * c + srow;
            gll16(vbase + (size_t)r * TT + i * 64 + sgr * 8, &SMEM[1][0][r][lg * 8]);
        }
        if (both) {
            #pragma unroll
            for (int c = 0; c < 2; c++) {
                int r = 32 * c + srow;
                gll16(vbase + (size_t)r * TT + (n0 + i) * 64 + sgr * 8, &SMEM[1][1][r][lg * 8]);
            }
        }
        // ---- wait K portion only (V stays in flight), barrier ----
        if (both) asm volatile("s_waitcnt vmcnt(4)" ::: "memory");
        else      asm volatile("s_waitcnt vmcnt(2)" ::: "memory");
        __builtin_amdgcn_s_barrier();

        const int kt = (s ? n0 : 0) + i;          // this wave's global key tile
        const bool active = (s == 0) || both;
        const bool diag = (kt == qj);
        bf16x8 pfrag[4];

        if (active) {
            #pragma unroll
            for (int mb = 0; mb < 2; mb++) {
                floatx16 sacc = (floatx16)(0.f);
                __builtin_amdgcn_s_setprio(1);
                #pragma unroll
                for (int kk = 0; kk < 4; kk++) {
                    bf16x8 kf = *(const bf16x8*)&SMEM[0][s][32 * mb + l32][((2 * kk + h) ^ xr) * 8];
                    sacc = __builtin_amdgcn_mfma_f32_32x32x16_bf16(kf, qf[kk], sacc, 0, 0, 0);
                }
                __builtin_amdgcn_s_setprio(0);
                float p[16];
                const int kmb = kt * 64 + 32 * mb + 4 * h;
                #pragma unroll
                for (int r = 0; r < 16; r++) {
                    float pv = __builtin_amdgcn_exp2f(sacc[r]);
                    if (diag) {
                        int ki = kmb + (r & 3) + 8 * (r >> 2);
                        if (ki > qw) pv = 0.f;
                    }
                    lsum += pv;
                    p[r] = pv;
                }
                #pragma unroll
                for (int half = 0; half < 2; half++) {
                    union { bf16x8 v; unsigned u[4]; } pk;
                    #pragma unroll
                    for (int i2 = 0; i2 < 4; i2++) {
                        unsigned ulo = __float_as_uint(p[half * 8 + 2 * i2]);
                        unsigned uhi = __float_as_uint(p[half * 8 + 2 * i2 + 1]);
                        pk.u[i2] = (ulo >> 16) | (uhi & 0xffff0000u);
                    }
                    pfrag[2 * mb + half] = pk.v;
                }
            }
        }

        // ---- V loads landed? drain + barrier, then PV ----
        asm volatile("s_waitcnt vmcnt(0)" ::: "memory");
        __builtin_amdgcn_s_barrier();

        if (active) {
            __builtin_amdgcn_s_setprio(1);
            #pragma unroll
            for (int mbo = 0; mbo < 2; mbo++) {
                #pragma unroll
                for (int kk = 0; kk < 4; kk++) {
                    bf16x8 vf = *(const bf16x8*)&SMEM[1][s][32 * mbo + l32][((2 * kk + h) ^ xr) * 8];
                    accO[mbo] = __builtin_amdgcn_mfma_f32_32x32x16_bf16(vf, pfrag[kk], accO[mbo], 0, 0, 0);
                }
            }
            __builtin_amdgcn_s_setprio(0);
        }
    }

    // ---- epilogue: cross-split combine in LDS, normalize, write Yb ----
    lsum += __shfl_xor(lsum, 32);
    __syncthreads();                                    // all LDS tile reads done
    float* Fb = (float*)&SMEM[0][0][0][0];              // 64 rows x 65 floats = 16640 B <= 32 KB
    float* Lb = Fb + 64 * 65;                           // 64 floats
    if (s == 1) {
        float* f = Fb + (size_t)(g * 32 + l32) * 65;    // stride 65: conflict-free
        #pragma unroll
        for (int mbo = 0; mbo < 2; mbo++)
            #pragma unroll
            for (int a = 0; a < 4; a++) {
                int d0 = 32 * mbo + 8 * a + 4 * h;
                f[d0 + 0] = accO[mbo][4 * a + 0];
                f[d0 + 1] = accO[mbo][4 * a + 1];
                f[d0 + 2] = accO[mbo][4 * a + 2];
                f[d0 + 3] = accO[mbo][4 * a + 3];
            }
        if (lane < 32) Lb[g * 32 + l32] = lsum;
    }
    __syncthreads();
    if (s == 0) {
        const float* f = Fb + (size_t)(g * 32 + l32) * 65;
        const float inv = 1.0f / (lsum + Lb[g * 32 + l32]);
        const int bb = bh >> 4, hh = bh & 15;
        unsigned short* orow = Yb + ((size_t)(bb * TT + qw)) * CC + hh * 64;
        #pragma unroll
        for (int mbo = 0; mbo < 2; mbo++)
            #pragma unroll
            for (int a = 0; a < 4; a++) {
                int d0 = 32 * mbo + 8 * a + 4 * h;
                ushort4 o4;
                o4.x = f2bf((accO[mbo][4 * a + 0] + f[d0 + 0]) * inv);
                o4.y = f2bf((accO[mbo][4 * a + 1] + f[d0 + 1]) * inv);
                o4.z = f2bf((accO[mbo][4 * a + 2] + f[d0 + 2]) * inv);
                o4.w = f2bf((accO[mbo][4 * a + 3] + f[d0 + 3]) * inv);
                *(ushort4*)(orow + d0) = o4;
            }
    }
}

extern "C" void kernel_launch(void* const* d_in, const int* in_sizes, int n_in,
                              void* d_out, int out_size, void* d_ws, size_t ws_size,
                              hipStream_t stream) {
    (void)in_sizes; (void)n_in; (void)out_size; (void)ws_size;
    const float* x  = (const float*)d_in[0];
    const float* Wq = (const float*)d_in[1];
    const float* Wk = (const float*)d_in[2];
    const float* Wv = (const float*)d_in[3];
    const float* Wo = (const float*)d_in[4];
    float* out = (float*)d_out;
    char* ws = (char*)d_ws;

    unsigned short* xb    = (unsigned short*)(ws + 0);                      //  8 MB
    unsigned short* wqkvb = (unsigned short*)(ws + (8ull  << 20));          //  6 MB
    unsigned short* wob   = (unsigned short*)(ws + (14ull << 20));          //  2 MB
    unsigned short* Qb    = (unsigned short*)(ws + (16ull << 20));          //  8 MB [BH,T,D] (pre-scaled)
    unsigned short* Kb    = (unsigned short*)(ws + (24ull << 20));          //  8 MB [BH,T,D]
    unsigned short* Vt    = (unsigned short*)(ws + (40ull << 20));          //  8 MB [BH,D,T] slot-permuted
    unsigned short* Yb    = (unsigned short*)(ws + (48ull << 20));          //  8 MB
    float2* tabQ = (float2*)(ws + (73ull << 20));                           // 512 KB
    float2* tabK = (float2*)(ws + (73ull << 20) + (512ull << 10));          // 512 KB

    cast_all_k<<<8448, 256, 0, stream>>>(x, Wq, Wk, Wv, Wo, xb, wqkvb, wob, tabQ, tabK);
    gemm_qkv_k<<<768, 256, 0, stream>>>(xb, wqkvb, tabQ, tabK, Qb, Kb, Vt);
    flash_k<<<1024, 256, 0, stream>>>(Qb, Kb, Vt, Yb);
    gemm_o_k<<<512, 256, 0, stream>>>(Yb, wob, out, 1024, 1024);
}

// Round 13
// 168.489 us; speedup vs baseline: 1.1293x; 1.1293x over previous
//
#include <hip/hip_runtime.h>

// Problem constants
#define BB 2
#define TT 2048
#define CC 1024
#define NH 16
#define HD 64

typedef __attribute__((ext_vector_type(8))) short bf16x8;
typedef __attribute__((ext_vector_type(4))) float floatx4;
typedef __attribute__((ext_vector_type(16))) float floatx16;

__device__ __forceinline__ unsigned short f2bf(float f) {
    union { float f; unsigned int u; } v; v.f = f;
    unsigned int u = v.u;
    u = (u + 0x7fffu + ((u >> 16) & 1u)) >> 16;   // RNE
    return (unsigned short)u;
}
__device__ __forceinline__ float bf2f(unsigned short u) {
    return __uint_as_float((unsigned)u << 16);
}

typedef __attribute__((address_space(3))) unsigned char* lds_ptr_t;
typedef const __attribute__((address_space(1))) unsigned char* glob_ptr_t;
__device__ __forceinline__ void gll16(const void* g, void* l) {
    __builtin_amdgcn_global_load_lds((glob_ptr_t)g, (lds_ptr_t)l, 16, 0, 0);
}

// ---------------- fused cast fp32 -> bf16 + RoPE table build ----------------
__global__ __launch_bounds__(256) void cast_all_k(const float* __restrict__ x,
                                                  const float* __restrict__ wq,
                                                  const float* __restrict__ wk,
                                                  const float* __restrict__ wv,
                                                  const float* __restrict__ wo,
                                                  unsigned short* __restrict__ xb,
                                                  unsigned short* __restrict__ wqkvb,
                                                  unsigned short* __restrict__ wob,
                                                  float2* __restrict__ tabQ,
                                                  float2* __restrict__ tabK) {
    if (blockIdx.x >= 8192) {   // RoPE tables: 2048 t x 32 pairs
        int idx = (blockIdx.x - 8192) * 256 + threadIdx.x;   // 0..65535
        int t = idx >> 5, j = idx & 31;
        const float C1 = 0.41524101186092f;        // log2(10000)/32
        const float I2PI = 0.15915494309189535f;
        float rev = (float)t * (__builtin_amdgcn_exp2f(-(float)j * C1) * I2PI);
        rev -= floorf(rev);
        float ang = rev * 6.2831853071796f;
        float c = __cosf(ang), s = __sinf(ang);
        const float qs = 0.18033688011112f;        // (1/8)*log2(e), folded into Q table
        tabK[idx] = make_float2(c, s);
        tabQ[idx] = make_float2(c * qs, s * qs);
        return;
    }
    int i = blockIdx.x * 256 + threadIdx.x;   // float4 index
    const float* src;
    unsigned short* dst;
    if (i < 1048576) {
        src = x + (size_t)i * 4;
        dst = xb + (size_t)i * 4;
    } else {
        int w   = (i - 1048576) >> 18;        // 0..3
        int off = (i - 1048576) & 262143;
        const float* s0 = (w == 0) ? wq : (w == 1) ? wk : (w == 2) ? wv : wo;
        unsigned short* d0 = (w == 3) ? wob : (wqkvb + (size_t)w * 1048576);
        src = s0 + (size_t)off * 4;
        dst = d0 + (size_t)off * 4;
    }
    float4 v = *(const float4*)src;
    ushort4 o;
    o.x = f2bf(v.x); o.y = f2bf(v.y); o.z = f2bf(v.z); o.w = f2bf(v.w);
    *(ushort4*)dst = o;
}

// ---------------- out-proj GEMM: 128x64 tile, BK=64, XOR-swizzled LDS, grid 512 (2 blk/CU) ----------------
__global__ __launch_bounds__(256, 2) void gemm_o_k(const unsigned short* __restrict__ A,
                                                   const unsigned short* __restrict__ Bt,
                                                   float* __restrict__ C, int N, int K) {
    __shared__ __align__(16) unsigned short As[128][64];
    __shared__ __align__(16) unsigned short Bs[64][64];
    const int tid  = threadIdx.x;
    const int wave = tid >> 6;
    const int lane = tid & 63;
    const int quad = lane >> 4;
    const int l16  = lane & 15;
    const int sw   = l16 & 7;             // fragment-read XOR key
    const int wr = (wave >> 1) * 64;      // wave row offset within 128
    const int wc = (wave & 1) * 32;       // wave col offset within 64
    const int bid = blockIdx.x;
    const int xcd = bid & 7, sl = bid >> 3;          // sl 0..63
    const int row0 = (xcd * 4 + (sl >> 4)) * 128;    // 32 row tiles
    const int col0 = (sl & 15) * 64;                 // 16 col tiles
    const int w8r = wave * 8 + (lane >> 3);
    const int cg  = ((lane & 7) ^ (lane >> 3)) * 8;  // global col (shorts), pre-swizzled
    const int cl  = (lane & 7) * 8;                  // phys LDS col (shorts)

    const unsigned short* Ap = A  + (size_t)(row0 + w8r) * K + cg;
    const unsigned short* Bp = Bt + (size_t)(col0 + w8r) * K + cg;

    floatx4 acc[4][2];
    #pragma unroll
    for (int i = 0; i < 4; i++)
        #pragma unroll
        for (int j = 0; j < 2; j++) acc[i][j] = (floatx4){0.f, 0.f, 0.f, 0.f};

    for (int k0 = 0; k0 < K; k0 += 64) {
        __syncthreads();
        #pragma unroll
        for (int isu = 0; isu < 4; isu++)
            gll16(Ap + (size_t)(isu * 32) * K + k0, &As[isu * 32 + w8r][cl]);
        #pragma unroll
        for (int isu = 0; isu < 2; isu++)
            gll16(Bp + (size_t)(isu * 32) * K + k0, &Bs[isu * 32 + w8r][cl]);
        __syncthreads();
        #pragma unroll
        for (int kk = 0; kk < 2; kk++) {
            bf16x8 af[4], bfr[2];
            #pragma unroll
            for (int i = 0; i < 4; i++)
                af[i]  = *(const bf16x8*)&As[wr + 16 * i + l16][((kk * 4 + quad) ^ sw) * 8];
            #pragma unroll
            for (int j = 0; j < 2; j++)
                bfr[j] = *(const bf16x8*)&Bs[wc + 16 * j + l16][((kk * 4 + quad) ^ sw) * 8];
            #pragma unroll
            for (int i = 0; i < 4; i++)
                #pragma unroll
                for (int j = 0; j < 2; j++)
                    acc[i][j] = __builtin_amdgcn_mfma_f32_16x16x32_bf16(af[i], bfr[j], acc[i][j], 0, 0, 0);
        }
    }

    #pragma unroll
    for (int i = 0; i < 4; i++)
        #pragma unroll
        for (int j = 0; j < 2; j++)
            #pragma unroll
            for (int r = 0; r < 4; r++) {
                int row = row0 + wr + 16 * i + quad * 4 + r;
                int col = col0 + wc + 16 * j + l16;
                C[(size_t)row * N + col] = acc[i][j][r];
            }
}

// ---------------- QKV GEMM: BK=64, XOR-swizzled LDS, table-RoPE LDS-bounce epilogue ----------------
__global__ __launch_bounds__(256) void gemm_qkv_k(const unsigned short* __restrict__ A,
                                                  const unsigned short* __restrict__ Bt,
                                                  const float2* __restrict__ tabQ,
                                                  const float2* __restrict__ tabK,
                                                  unsigned short* __restrict__ Qb,
                                                  unsigned short* __restrict__ Kb,
                                                  unsigned short* __restrict__ Vb) {
    __shared__ __align__(16) unsigned short SMEM[128 * 128];   // 32 KB: As+Bs in loop, Eb in epilogue
    unsigned short (*As)[64] = (unsigned short(*)[64])SMEM;
    unsigned short (*Bs)[64] = (unsigned short(*)[64])(SMEM + 128 * 64);
    unsigned short (*Eb)[128] = (unsigned short(*)[128])SMEM;
    const int K = 1024;
    const int tid  = threadIdx.x;
    const int wave = tid >> 6;
    const int lane = tid & 63;
    const int quad = lane >> 4;
    const int l16  = lane & 15;
    const int sw   = l16 & 7;
    const int wr = (wave >> 1) * 64;
    const int wc = (wave & 1) * 64;
    const int bid = blockIdx.x;
    const int xcd = bid & 7, sl = bid >> 3;          // sl 0..95
    const int row0 = (xcd * 4 + sl / 24) * 128;
    const int col0 = (sl % 24) * 128;
    const int w8r = wave * 8 + (lane >> 3);
    const int cg  = ((lane & 7) ^ (lane >> 3)) * 8;
    const int cl  = (lane & 7) * 8;

    const unsigned short* Ap = A  + (size_t)(row0 + w8r) * K + cg;
    const unsigned short* Bp = Bt + (size_t)(col0 + w8r) * K + cg;

    floatx4 acc[4][4];
    #pragma unroll
    for (int i = 0; i < 4; i++)
        #pragma unroll
        for (int j = 0; j < 4; j++) acc[i][j] = (floatx4){0.f, 0.f, 0.f, 0.f};

    for (int k0 = 0; k0 < K; k0 += 64) {
        __syncthreads();
        #pragma unroll
        for (int isu = 0; isu < 4; isu++) {
            gll16(Ap + (size_t)(isu * 32) * K + k0, &As[isu * 32 + w8r][cl]);
            gll16(Bp + (size_t)(isu * 32) * K + k0, &Bs[isu * 32 + w8r][cl]);
        }
        __syncthreads();
        #pragma unroll
        for (int kk = 0; kk < 2; kk++) {
            bf16x8 af[4], bfr[4];
            #pragma unroll
            for (int i = 0; i < 4; i++)
                af[i]  = *(const bf16x8*)&As[wr + 16 * i + l16][((kk * 4 + quad) ^ sw) * 8];
            #pragma unroll
            for (int j = 0; j < 4; j++)
                bfr[j] = *(const bf16x8*)&Bs[wc + 16 * j + l16][((kk * 4 + quad) ^ sw) * 8];
            #pragma unroll
            for (int i = 0; i < 4; i++)
                #pragma unroll
                for (int j = 0; j < 4; j++)
                    acc[i][j] = __builtin_amdgcn_mfma_f32_16x16x32_bf16(af[i], bfr[j], acc[i][j], 0, 0, 0);
        }
    }

    // ---- Phase 1: acc -> Eb (bf16), XOR-granule swizzle ----
    __syncthreads();
    #pragma unroll
    for (int i = 0; i < 4; i++)
        #pragma unroll
        for (int j = 0; j < 4; j++)
            #pragma unroll
            for (int r = 0; r < 4; r++) {
                int erow = wr + 16 * i + quad * 4 + r;
                int col  = wc + 16 * j + l16;
                int pcol = (((col >> 3) ^ (erow & 15)) << 3) | (col & 7);
                Eb[erow][pcol] = f2bf(acc[i][j][r]);
            }
    __syncthreads();

    // ---- Phase 2: row-wise readback, RoPE via table, coalesced stores ----
    const int row  = tid >> 1;            // 0..127
    const int half = tid & 1;
    const int grow = row0 + row;
    const int t    = grow & (TT - 1);
    const int bb   = grow >> 11;
    const int sect = col0 >> 10;                        // 0=Q,1=K,2=V
    const int hh   = ((col0 & 1023) >> 6) + half;       // head
    union { int4 q[8]; unsigned short u[64]; } raw;
    #pragma unroll
    for (int i = 0; i < 8; i++) {
        int pg = (half * 8 + i) ^ (row & 15);
        raw.q[i] = *(const int4*)&Eb[row][pg << 3];
    }
    size_t obase = ((size_t)(bb * NH + hh) * TT + t) * 64;
    if (sect == 2) {
        #pragma unroll
        for (int i = 0; i < 8; i++) *(int4*)(Vb + obase + 8 * i) = raw.q[i];
    } else {
        const float4* tab = (const float4*)((sect ? tabK : tabQ) + (size_t)t * 32);
        unsigned short* dst = sect ? Kb : Qb;
        union { int4 q[8]; unsigned short u[64]; } o;
        #pragma unroll
        for (int i = 0; i < 16; i++) {
            float4 cs = tab[i];      // {c0,s0,c1,s1} for pairs j=2i, 2i+1
            int j0 = 2 * i, j1 = 2 * i + 1;
            float a0 = bf2f(raw.u[j0]), b0 = bf2f(raw.u[j0 + 32]);
            float a1 = bf2f(raw.u[j1]), b1 = bf2f(raw.u[j1 + 32]);
            o.u[j0]      = f2bf(a0 * cs.x - b0 * cs.y);
            o.u[j0 + 32] = f2bf(b0 * cs.x + a0 * cs.y);
            o.u[j1]      = f2bf(a1 * cs.z - b1 * cs.w);
            o.u[j1 + 32] = f2bf(b1 * cs.z + a1 * cs.w);
        }
        #pragma unroll
        for (int i = 0; i < 8; i++) *(int4*)(dst + obase + 8 * i) = o.q[i];
    }
}

// ---------------- V transpose: Vb [BH,T,D] -> Vt [BH,D,T], key slot-permuted ----------------
__global__ __launch_bounds__(256) void vtr_k(const unsigned short* __restrict__ Vb,
                                             unsigned short* __restrict__ Vt) {
    __shared__ __align__(16) unsigned short Vsh[64][70];
    const int tid = threadIdx.x;
    const int tt = blockIdx.x;    // t-tile 0..31
    const int bh = blockIdx.y;    // 0..31
    const int sr = tid >> 2;
    const int sc = (tid & 3) * 16;
    const unsigned short* src = Vb + ((size_t)bh * TT + tt * 64 + sr) * 64 + sc;
    *(int4*)&Vsh[sr][sc]     = *(const int4*)src;
    *(int4*)&Vsh[sr][sc + 8] = *(const int4*)(src + 8);
    __syncthreads();
    const int dr = tid >> 2;
    const int tc = (tid & 3) * 16;
    unsigned short tv[16];
    #pragma unroll
    for (int i = 0; i < 16; i++) {
        int x = tc + i;
        int key = (x & ~15) + (x & 3) + ((x >> 2) & 1) * 8 + ((x >> 3) & 1) * 4;
        tv[i] = Vsh[key][dr];
    }
    size_t vo = ((size_t)bh * 64 + dr) * TT + tt * 64 + tc;
    *(int4*)(Vt + vo)     = *(int4*)&tv[0];
    *(int4*)(Vt + vo + 8) = *(int4*)&tv[8];
}

// ---------------- flash attention: intra-block key-split, gll16-direct staging ----------------
// R10-proven: split-wait staging (T4-lite). Issue K-loads then V-loads; wait only the K
// portion (counted vmcnt) before QK^T; V loads land under QK+softmax; vmcnt(0)
// + barrier before PV.
__global__ __launch_bounds__(256, 4) void flash_k(const unsigned short* __restrict__ Qb,
                                                  const unsigned short* __restrict__ Kb,
                                                  const unsigned short* __restrict__ Vt,
                                                  unsigned short* __restrict__ Yb) {
    __shared__ __align__(16) unsigned short SMEM[2][2][64][64];   // [K/V][split][row][col] 32 KB
    const int tid  = threadIdx.x;
    const int wave = tid >> 6;
    const int lane = tid & 63;
    const int h    = lane >> 5;
    const int l32  = lane & 31;
    const int g    = wave >> 1;                 // q-row group 0/1
    const int s    = wave & 1;                  // key split 0/1
    const int j    = blockIdx.x >> 5;           // 0..31
    const int qj   = (j < 16) ? (31 - j) : (j - 16);
    const int bh   = blockIdx.x & 31;
    const int q0   = qj * 64;
    const int qw   = q0 + g * 32 + l32;         // this lane's q row
    const int nt   = qj + 1;                    // causal key tiles
    const int n0   = (nt + 1) >> 1;             // split0 tiles (= loop count)
    const int n1   = nt - n0;                   // split1 tiles (n0-1 or n0)
    // staging decomposition: lane -> row l8, granule lg; source granule pre-swizzled
    const int l8  = lane >> 3;                  // 0..7
    const int lg  = lane & 7;                   // dst granule (16B)
    const int srow = wave * 8 + l8;             // 0..31 (call c adds 32*c)
    const int sgr  = lg ^ l8;                   // swizzled source granule
    const int xr   = l32 & 7;                   // fragment-read XOR key

    bf16x8 qf[4];
    {
        const unsigned short* qp = Qb + ((size_t)bh * TT + qw) * 64 + h * 8;
        #pragma unroll
        for (int kk = 0; kk < 4; kk++) qf[kk] = *(const bf16x8*)(qp + kk * 16);
    }

    floatx16 accO[2];
    accO[0] = (floatx16)(0.f);
    accO[1] = (floatx16)(0.f);
    float lsum = 0.f;

    const unsigned short* kbase = Kb + (size_t)bh * TT * 64;
    const unsigned short* vbase = Vt + (size_t)bh * 64 * TT;

    for (int i = 0; i < n0; i++) {
        __syncthreads();                         // prev tile reads complete (vmcnt already 0)
        const bool both = (i < n1);
        // ---- issue K loads first (both splits), then V loads ----
        #pragma unroll
        for (int c = 0; c < 2; c++) {
            int r = 32 * c + srow;
            gll16(kbase + ((size_t)(i * 64) + r) * 64 + sgr * 8, &SMEM[0][0][r][lg * 8]);
        }
        if (both) {
            #pragma unroll
            for (int c = 0; c < 2; c++) {
                int r = 32 * c + srow;
                gll16(kbase + ((size_t)((n0 + i) * 64) + r) * 64 + sgr * 8, &SMEM[0][1][r][lg * 8]);
            }
        }
        #pragma unroll
        for (int c = 0; c < 2; c++) {
            int r = 32 * c + srow;
            gll16(vbase + (size_t)r * TT + i * 64 + sgr * 8, &SMEM[1][0][r][lg * 8]);
        }
        if (both) {
            #pragma unroll
            for (int c = 0; c < 2; c++) {
                int r = 32 * c + srow;
                gll16(vbase + (size_t)r * TT + (n0 + i) * 64 + sgr * 8, &SMEM[1][1][r][lg * 8]);
            }
        }
        // ---- wait K portion only (V stays in flight), barrier ----
        if (both) asm volatile("s_waitcnt vmcnt(4)" ::: "memory");
        else      asm volatile("s_waitcnt vmcnt(2)" ::: "memory");
        __builtin_amdgcn_s_barrier();

        const int kt = (s ? n0 : 0) + i;          // this wave's global key tile
        const bool active = (s == 0) || both;
        const bool diag = (kt == qj);
        bf16x8 pfrag[4];

        if (active) {
            #pragma unroll
            for (int mb = 0; mb < 2; mb++) {
                floatx16 sacc = (floatx16)(0.f);
                __builtin_amdgcn_s_setprio(1);
                #pragma unroll
                for (int kk = 0; kk < 4; kk++) {
                    bf16x8 kf = *(const bf16x8*)&SMEM[0][s][32 * mb + l32][((2 * kk + h) ^ xr) * 8];
                    sacc = __builtin_amdgcn_mfma_f32_32x32x16_bf16(kf, qf[kk], sacc, 0, 0, 0);
                }
                __builtin_amdgcn_s_setprio(0);
                float p[16];
                const int kmb = kt * 64 + 32 * mb + 4 * h;
                #pragma unroll
                for (int r = 0; r < 16; r++) {
                    float pv = __builtin_amdgcn_exp2f(sacc[r]);
                    if (diag) {
                        int ki = kmb + (r & 3) + 8 * (r >> 2);
                        if (ki > qw) pv = 0.f;
                    }
                    lsum += pv;
                    p[r] = pv;
                }
                #pragma unroll
                for (int half = 0; half < 2; half++) {
                    union { bf16x8 v; unsigned u[4]; } pk;
                    #pragma unroll
                    for (int i2 = 0; i2 < 4; i2++) {
                        unsigned ulo = __float_as_uint(p[half * 8 + 2 * i2]);
                        unsigned uhi = __float_as_uint(p[half * 8 + 2 * i2 + 1]);
                        pk.u[i2] = (ulo >> 16) | (uhi & 0xffff0000u);
                    }
                    pfrag[2 * mb + half] = pk.v;
                }
            }
        }

        // ---- V loads landed? drain + barrier, then PV ----
        asm volatile("s_waitcnt vmcnt(0)" ::: "memory");
        __builtin_amdgcn_s_barrier();

        if (active) {
            __builtin_amdgcn_s_setprio(1);
            #pragma unroll
            for (int mbo = 0; mbo < 2; mbo++) {
                #pragma unroll
                for (int kk = 0; kk < 4; kk++) {
                    bf16x8 vf = *(const bf16x8*)&SMEM[1][s][32 * mbo + l32][((2 * kk + h) ^ xr) * 8];
                    accO[mbo] = __builtin_amdgcn_mfma_f32_32x32x16_bf16(vf, pfrag[kk], accO[mbo], 0, 0, 0);
                }
            }
            __builtin_amdgcn_s_setprio(0);
        }
    }

    // ---- epilogue: cross-split combine in LDS, normalize, write Yb ----
    lsum += __shfl_xor(lsum, 32);
    __syncthreads();                                    // all LDS tile reads done
    float* Fb = (float*)&SMEM[0][0][0][0];              // 64 rows x 65 floats = 16640 B <= 32 KB
    float* Lb = Fb + 64 * 65;                           // 64 floats
    if (s == 1) {
        float* f = Fb + (size_t)(g * 32 + l32) * 65;    // stride 65: conflict-free
        #pragma unroll
        for (int mbo = 0; mbo < 2; mbo++)
            #pragma unroll
            for (int a = 0; a < 4; a++) {
                int d0 = 32 * mbo + 8 * a + 4 * h;
                f[d0 + 0] = accO[mbo][4 * a + 0];
                f[d0 + 1] = accO[mbo][4 * a + 1];
                f[d0 + 2] = accO[mbo][4 * a + 2];
                f[d0 + 3] = accO[mbo][4 * a + 3];
            }
        if (lane < 32) Lb[g * 32 + l32] = lsum;
    }
    __syncthreads();
    if (s == 0) {
        const float* f = Fb + (size_t)(g * 32 + l32) * 65;
        const float inv = 1.0f / (lsum + Lb[g * 32 + l32]);
        const int bb = bh >> 4, hh = bh & 15;
        unsigned short* orow = Yb + ((size_t)(bb * TT + qw)) * CC + hh * 64;
        #pragma unroll
        for (int mbo = 0; mbo < 2; mbo++)
            #pragma unroll
            for (int a = 0; a < 4; a++) {
                int d0 = 32 * mbo + 8 * a + 4 * h;
                ushort4 o4;
                o4.x = f2bf((accO[mbo][4 * a + 0] + f[d0 + 0]) * inv);
                o4.y = f2bf((accO[mbo][4 * a + 1] + f[d0 + 1]) * inv);
                o4.z = f2bf((accO[mbo][4 * a + 2] + f[d0 + 2]) * inv);
                o4.w = f2bf((accO[mbo][4 * a + 3] + f[d0 + 3]) * inv);
                *(ushort4*)(orow + d0) = o4;
            }
    }
}

extern "C" void kernel_launch(void* const* d_in, const int* in_sizes, int n_in,
                              void* d_out, int out_size, void* d_ws, size_t ws_size,
                              hipStream_t stream) {
    (void)in_sizes; (void)n_in; (void)out_size; (void)ws_size;
    const float* x  = (const float*)d_in[0];
    const float* Wq = (const float*)d_in[1];
    const float* Wk = (const float*)d_in[2];
    const float* Wv = (const float*)d_in[3];
    const float* Wo = (const float*)d_in[4];
    float* out = (float*)d_out;
    char* ws = (char*)d_ws;

    unsigned short* xb    = (unsigned short*)(ws + 0);                      //  8 MB
    unsigned short* wqkvb = (unsigned short*)(ws + (8ull  << 20));          //  6 MB
    unsigned short* wob   = (unsigned short*)(ws + (14ull << 20));          //  2 MB
    unsigned short* Qb    = (unsigned short*)(ws + (16ull << 20));          //  8 MB [BH,T,D] (pre-scaled)
    unsigned short* Kb    = (unsigned short*)(ws + (24ull << 20));          //  8 MB [BH,T,D]
    unsigned short* Vb    = (unsigned short*)(ws + (32ull << 20));          //  8 MB [BH,T,D]
    unsigned short* Vt    = (unsigned short*)(ws + (40ull << 20));          //  8 MB [BH,D,T] slot-permuted
    unsigned short* Yb    = (unsigned short*)(ws + (48ull << 20));          //  8 MB
    float2* tabQ = (float2*)(ws + (73ull << 20));                           // 512 KB
    float2* tabK = (float2*)(ws + (73ull << 20) + (512ull << 10));          // 512 KB

    cast_all_k<<<8448, 256, 0, stream>>>(x, Wq, Wk, Wv, Wo, xb, wqkvb, wob, tabQ, tabK);
    gemm_qkv_k<<<768, 256, 0, stream>>>(xb, wqkvb, tabQ, tabK, Qb, Kb, Vb);
    vtr_k<<<dim3(32, 32), 256, 0, stream>>>(Vb, Vt);
    flash_k<<<1024, 256, 0, stream>>>(Qb, Kb, Vt, Yb);
    gemm_o_k<<<512, 256, 0, stream>>>(Yb, wob, out, 1024, 1024);
}

// Round 14
// 166.429 us; speedup vs baseline: 1.1433x; 1.0124x over previous
//
#include <hip/hip_runtime.h>

// Problem constants
#define BB 2
#define TT 2048
#define CC 1024
#define NH 16
#define HD 64

typedef __attribute__((ext_vector_type(8))) short bf16x8;
typedef __attribute__((ext_vector_type(4))) float floatx4;
typedef __attribute__((ext_vector_type(16))) float floatx16;

__device__ __forceinline__ unsigned short f2bf(float f) {
    union { float f; unsigned int u; } v; v.f = f;
    unsigned int u = v.u;
    u = (u + 0x7fffu + ((u >> 16) & 1u)) >> 16;   // RNE
    return (unsigned short)u;
}
__device__ __forceinline__ float bf2f(unsigned short u) {
    return __uint_as_float((unsigned)u << 16);
}

typedef __attribute__((address_space(3))) unsigned char* lds_ptr_t;
typedef const __attribute__((address_space(1))) unsigned char* glob_ptr_t;
__device__ __forceinline__ void gll16(const void* g, void* l) {
    __builtin_amdgcn_global_load_lds((glob_ptr_t)g, (lds_ptr_t)l, 16, 0, 0);
}

// ---------------- fused cast fp32 -> bf16 + RoPE table build ----------------
__global__ __launch_bounds__(256) void cast_all_k(const float* __restrict__ x,
                                                  const float* __restrict__ wq,
                                                  const float* __restrict__ wk,
                                                  const float* __restrict__ wv,
                                                  const float* __restrict__ wo,
                                                  unsigned short* __restrict__ xb,
                                                  unsigned short* __restrict__ wqkvb,
                                                  unsigned short* __restrict__ wob,
                                                  float2* __restrict__ tabQ,
                                                  float2* __restrict__ tabK) {
    if (blockIdx.x >= 8192) {   // RoPE tables: 2048 t x 32 pairs
        int idx = (blockIdx.x - 8192) * 256 + threadIdx.x;   // 0..65535
        int t = idx >> 5, j = idx & 31;
        const float C1 = 0.41524101186092f;        // log2(10000)/32
        const float I2PI = 0.15915494309189535f;
        float rev = (float)t * (__builtin_amdgcn_exp2f(-(float)j * C1) * I2PI);
        rev -= floorf(rev);
        float ang = rev * 6.2831853071796f;
        float c = __cosf(ang), s = __sinf(ang);
        const float qs = 0.18033688011112f;        // (1/8)*log2(e), folded into Q table
        tabK[idx] = make_float2(c, s);
        tabQ[idx] = make_float2(c * qs, s * qs);
        return;
    }
    int i = blockIdx.x * 256 + threadIdx.x;   // float4 index
    const float* src;
    unsigned short* dst;
    if (i < 1048576) {
        src = x + (size_t)i * 4;
        dst = xb + (size_t)i * 4;
    } else {
        int w   = (i - 1048576) >> 18;        // 0..3
        int off = (i - 1048576) & 262143;
        const float* s0 = (w == 0) ? wq : (w == 1) ? wk : (w == 2) ? wv : wo;
        unsigned short* d0 = (w == 3) ? wob : (wqkvb + (size_t)w * 1048576);
        src = s0 + (size_t)off * 4;
        dst = d0 + (size_t)off * 4;
    }
    float4 v = *(const float4*)src;
    ushort4 o;
    o.x = f2bf(v.x); o.y = f2bf(v.y); o.z = f2bf(v.z); o.w = f2bf(v.w);
    *(ushort4*)dst = o;
}

// ---------------- out-proj GEMM: 128x64 tile, BK=64, XOR-swizzled LDS, grid 512 (2 blk/CU) ----------------
__global__ __launch_bounds__(256, 2) void gemm_o_k(const unsigned short* __restrict__ A,
                                                   const unsigned short* __restrict__ Bt,
                                                   float* __restrict__ C, int N, int K) {
    __shared__ __align__(16) unsigned short As[128][64];
    __shared__ __align__(16) unsigned short Bs[64][64];
    const int tid  = threadIdx.x;
    const int wave = tid >> 6;
    const int lane = tid & 63;
    const int quad = lane >> 4;
    const int l16  = lane & 15;
    const int sw   = l16 & 7;             // fragment-read XOR key
    const int wr = (wave >> 1) * 64;      // wave row offset within 128
    const int wc = (wave & 1) * 32;       // wave col offset within 64
    const int bid = blockIdx.x;
    const int xcd = bid & 7, sl = bid >> 3;          // sl 0..63
    const int row0 = (xcd * 4 + (sl >> 4)) * 128;    // 32 row tiles
    const int col0 = (sl & 15) * 64;                 // 16 col tiles
    const int w8r = wave * 8 + (lane >> 3);
    const int cg  = ((lane & 7) ^ (lane >> 3)) * 8;  // global col (shorts), pre-swizzled
    const int cl  = (lane & 7) * 8;                  // phys LDS col (shorts)

    const unsigned short* Ap = A  + (size_t)(row0 + w8r) * K + cg;
    const unsigned short* Bp = Bt + (size_t)(col0 + w8r) * K + cg;

    floatx4 acc[4][2];
    #pragma unroll
    for (int i = 0; i < 4; i++)
        #pragma unroll
        for (int j = 0; j < 2; j++) acc[i][j] = (floatx4){0.f, 0.f, 0.f, 0.f};

    for (int k0 = 0; k0 < K; k0 += 64) {
        __syncthreads();
        #pragma unroll
        for (int isu = 0; isu < 4; isu++)
            gll16(Ap + (size_t)(isu * 32) * K + k0, &As[isu * 32 + w8r][cl]);
        #pragma unroll
        for (int isu = 0; isu < 2; isu++)
            gll16(Bp + (size_t)(isu * 32) * K + k0, &Bs[isu * 32 + w8r][cl]);
        __syncthreads();
        #pragma unroll
        for (int kk = 0; kk < 2; kk++) {
            bf16x8 af[4], bfr[2];
            #pragma unroll
            for (int i = 0; i < 4; i++)
                af[i]  = *(const bf16x8*)&As[wr + 16 * i + l16][((kk * 4 + quad) ^ sw) * 8];
            #pragma unroll
            for (int j = 0; j < 2; j++)
                bfr[j] = *(const bf16x8*)&Bs[wc + 16 * j + l16][((kk * 4 + quad) ^ sw) * 8];
            #pragma unroll
            for (int i = 0; i < 4; i++)
                #pragma unroll
                for (int j = 0; j < 2; j++)
                    acc[i][j] = __builtin_amdgcn_mfma_f32_16x16x32_bf16(af[i], bfr[j], acc[i][j], 0, 0, 0);
        }
    }

    #pragma unroll
    for (int i = 0; i < 4; i++)
        #pragma unroll
        for (int j = 0; j < 2; j++)
            #pragma unroll
            for (int r = 0; r < 4; r++) {
                int row = row0 + wr + 16 * i + quad * 4 + r;
                int col = col0 + wc + 16 * j + l16;
                C[(size_t)row * N + col] = acc[i][j][r];
            }
}

// ---------------- QKV GEMM: BK=64, XOR-swizzled LDS, table-RoPE LDS-bounce epilogue ----------------
__global__ __launch_bounds__(256) void gemm_qkv_k(const unsigned short* __restrict__ A,
                                                  const unsigned short* __restrict__ Bt,
                                                  const float2* __restrict__ tabQ,
                                                  const float2* __restrict__ tabK,
                                                  unsigned short* __restrict__ Qb,
                                                  unsigned short* __restrict__ Kb,
                                                  unsigned short* __restrict__ Vb) {
    __shared__ __align__(16) unsigned short SMEM[128 * 128];   // 32 KB: As+Bs in loop, Eb in epilogue
    unsigned short (*As)[64] = (unsigned short(*)[64])SMEM;
    unsigned short (*Bs)[64] = (unsigned short(*)[64])(SMEM + 128 * 64);
    unsigned short (*Eb)[128] = (unsigned short(*)[128])SMEM;
    const int K = 1024;
    const int tid  = threadIdx.x;
    const int wave = tid >> 6;
    const int lane = tid & 63;
    const int quad = lane >> 4;
    const int l16  = lane & 15;
    const int sw   = l16 & 7;
    const int wr = (wave >> 1) * 64;
    const int wc = (wave & 1) * 64;
    const int bid = blockIdx.x;
    const int xcd = bid & 7, sl = bid >> 3;          // sl 0..95
    const int row0 = (xcd * 4 + sl / 24) * 128;
    const int col0 = (sl % 24) * 128;
    const int w8r = wave * 8 + (lane >> 3);
    const int cg  = ((lane & 7) ^ (lane >> 3)) * 8;
    const int cl  = (lane & 7) * 8;

    const unsigned short* Ap = A  + (size_t)(row0 + w8r) * K + cg;
    const unsigned short* Bp = Bt + (size_t)(col0 + w8r) * K + cg;

    floatx4 acc[4][4];
    #pragma unroll
    for (int i = 0; i < 4; i++)
        #pragma unroll
        for (int j = 0; j < 4; j++) acc[i][j] = (floatx4){0.f, 0.f, 0.f, 0.f};

    for (int k0 = 0; k0 < K; k0 += 64) {
        __syncthreads();
        #pragma unroll
        for (int isu = 0; isu < 4; isu++) {
            gll16(Ap + (size_t)(isu * 32) * K + k0, &As[isu * 32 + w8r][cl]);
            gll16(Bp + (size_t)(isu * 32) * K + k0, &Bs[isu * 32 + w8r][cl]);
        }
        __syncthreads();
        #pragma unroll
        for (int kk = 0; kk < 2; kk++) {
            bf16x8 af[4], bfr[4];
            #pragma unroll
            for (int i = 0; i < 4; i++)
                af[i]  = *(const bf16x8*)&As[wr + 16 * i + l16][((kk * 4 + quad) ^ sw) * 8];
            #pragma unroll
            for (int j = 0; j < 4; j++)
                bfr[j] = *(const bf16x8*)&Bs[wc + 16 * j + l16][((kk * 4 + quad) ^ sw) * 8];
            #pragma unroll
            for (int i = 0; i < 4; i++)
                #pragma unroll
                for (int j = 0; j < 4; j++)
                    acc[i][j] = __builtin_amdgcn_mfma_f32_16x16x32_bf16(af[i], bfr[j], acc[i][j], 0, 0, 0);
        }
    }

    // ---- Phase 1: acc -> Eb (bf16), XOR-granule swizzle ----
    __syncthreads();
    #pragma unroll
    for (int i = 0; i < 4; i++)
        #pragma unroll
        for (int j = 0; j < 4; j++)
            #pragma unroll
            for (int r = 0; r < 4; r++) {
                int erow = wr + 16 * i + quad * 4 + r;
                int col  = wc + 16 * j + l16;
                int pcol = (((col >> 3) ^ (erow & 15)) << 3) | (col & 7);
                Eb[erow][pcol] = f2bf(acc[i][j][r]);
            }
    __syncthreads();

    // ---- Phase 2: row-wise readback, RoPE via table, coalesced stores ----
    const int row  = tid >> 1;            // 0..127
    const int half = tid & 1;
    const int grow = row0 + row;
    const int t    = grow & (TT - 1);
    const int bb   = grow >> 11;
    const int sect = col0 >> 10;                        // 0=Q,1=K,2=V
    const int hh   = ((col0 & 1023) >> 6) + half;       // head
    union { int4 q[8]; unsigned short u[64]; } raw;
    #pragma unroll
    for (int i = 0; i < 8; i++) {
        int pg = (half * 8 + i) ^ (row & 15);
        raw.q[i] = *(const int4*)&Eb[row][pg << 3];
    }
    size_t obase = ((size_t)(bb * NH + hh) * TT + t) * 64;
    if (sect == 2) {
        #pragma unroll
        for (int i = 0; i < 8; i++) *(int4*)(Vb + obase + 8 * i) = raw.q[i];
    } else {
        const float4* tab = (const float4*)((sect ? tabK : tabQ) + (size_t)t * 32);
        unsigned short* dst = sect ? Kb : Qb;
        union { int4 q[8]; unsigned short u[64]; } o;
        #pragma unroll
        for (int i = 0; i < 16; i++) {
            float4 cs = tab[i];      // {c0,s0,c1,s1} for pairs j=2i, 2i+1
            int j0 = 2 * i, j1 = 2 * i + 1;
            float a0 = bf2f(raw.u[j0]), b0 = bf2f(raw.u[j0 + 32]);
            float a1 = bf2f(raw.u[j1]), b1 = bf2f(raw.u[j1 + 32]);
            o.u[j0]      = f2bf(a0 * cs.x - b0 * cs.y);
            o.u[j0 + 32] = f2bf(b0 * cs.x + a0 * cs.y);
            o.u[j1]      = f2bf(a1 * cs.z - b1 * cs.w);
            o.u[j1 + 32] = f2bf(b1 * cs.z + a1 * cs.w);
        }
        #pragma unroll
        for (int i = 0; i < 8; i++) *(int4*)(dst + obase + 8 * i) = o.q[i];
    }
}

// ---------------- V transpose: Vb [BH,T,D] -> Vt [BH,D,T], key slot-permuted ----------------
__global__ __launch_bounds__(256) void vtr_k(const unsigned short* __restrict__ Vb,
                                             unsigned short* __restrict__ Vt) {
    __shared__ __align__(16) unsigned short Vsh[64][70];
    const int tid = threadIdx.x;
    const int tt = blockIdx.x;    // t-tile 0..31
    const int bh = blockIdx.y;    // 0..31
    const int sr = tid >> 2;
    const int sc = (tid & 3) * 16;
    const unsigned short* src = Vb + ((size_t)bh * TT + tt * 64 + sr) * 64 + sc;
    *(int4*)&Vsh[sr][sc]     = *(const int4*)src;
    *(int4*)&Vsh[sr][sc + 8] = *(const int4*)(src + 8);
    __syncthreads();
    const int dr = tid >> 2;
    const int tc = (tid & 3) * 16;
    unsigned short tv[16];
    #pragma unroll
    for (int i = 0; i < 16; i++) {
        int x = tc + i;
        int key = (x & ~15) + (x & 3) + ((x >> 2) & 1) * 8 + ((x >> 3) & 1) * 4;
        tv[i] = Vsh[key][dr];
    }
    size_t vo = ((size_t)bh * 64 + dr) * TT + tt * 64 + tc;
    *(int4*)(Vt + vo)     = *(int4*)&tv[0];
    *(int4*)(Vt + vo + 8) = *(int4*)&tv[8];
}

// ---------------- flash attention: intra-block key-split, gll16-direct staging ----------------
// R14: full pipelined issue. K(i+1) issued after the pre-PV barrier (K region free,
// latency hides under PV(i)); V(i+1) issued after the post-PV barrier (V region free,
// latency hides under QK(i+1)). 3 barriers/iter unchanged; vmcnt(#V) at top isolates K.
__global__ __launch_bounds__(256, 4) void flash_k(const unsigned short* __restrict__ Qb,
                                                  const unsigned short* __restrict__ Kb,
                                                  const unsigned short* __restrict__ Vt,
                                                  unsigned short* __restrict__ Yb) {
    __shared__ __align__(16) unsigned short SMEM[2][2][64][64];   // [K/V][split][row][col] 32 KB
    const int tid  = threadIdx.x;
    const int wave = tid >> 6;
    const int lane = tid & 63;
    const int h    = lane >> 5;
    const int l32  = lane & 31;
    const int g    = wave >> 1;                 // q-row group 0/1
    const int s    = wave & 1;                  // key split 0/1
    const int j    = blockIdx.x >> 5;           // 0..31
    const int qj   = (j < 16) ? (31 - j) : (j - 16);
    const int bh   = blockIdx.x & 31;
    const int q0   = qj * 64;
    const int qw   = q0 + g * 32 + l32;         // this lane's q row
    const int nt   = qj + 1;                    // causal key tiles
    const int n0   = (nt + 1) >> 1;             // split0 tiles (= loop count)
    const int n1   = nt - n0;                   // split1 tiles (n0-1 or n0)
    // staging decomposition: lane -> row l8, granule lg; source granule pre-swizzled
    const int l8  = lane >> 3;                  // 0..7
    const int lg  = lane & 7;                   // dst granule (16B)
    const int srow = wave * 8 + l8;             // 0..31 (call c adds 32*c)
    const int sgr  = lg ^ l8;                   // swizzled source granule
    const int xr   = l32 & 7;                   // fragment-read XOR key

    bf16x8 qf[4];
    {
        const unsigned short* qp = Qb + ((size_t)bh * TT + qw) * 64 + h * 8;
        #pragma unroll
        for (int kk = 0; kk < 4; kk++) qf[kk] = *(const bf16x8*)(qp + kk * 16);
    }

    floatx16 accO[2];
    accO[0] = (floatx16)(0.f);
    accO[1] = (floatx16)(0.f);
    float lsum = 0.f;

    const unsigned short* kbase = Kb + (size_t)bh * TT * 64;
    const unsigned short* vbase = Vt + (size_t)bh * 64 * TT;

    // ---- prologue: issue K(0) then V(0) ----
    {
        const bool both0 = (0 < n1);
        #pragma unroll
        for (int c = 0; c < 2; c++) {
            int r = 32 * c + srow;
            gll16(kbase + (size_t)r * 64 + sgr * 8, &SMEM[0][0][r][lg * 8]);
        }
        if (both0) {
            #pragma unroll
            for (int c = 0; c < 2; c++) {
                int r = 32 * c + srow;
                gll16(kbase + ((size_t)(n0 * 64) + r) * 64 + sgr * 8, &SMEM[0][1][r][lg * 8]);
            }
        }
        #pragma unroll
        for (int c = 0; c < 2; c++) {
            int r = 32 * c + srow;
            gll16(vbase + (size_t)r * TT + sgr * 8, &SMEM[1][0][r][lg * 8]);
        }
        if (both0) {
            #pragma unroll
            for (int c = 0; c < 2; c++) {
                int r = 32 * c + srow;
                gll16(vbase + (size_t)r * TT + n0 * 64 + sgr * 8, &SMEM[1][1][r][lg * 8]);
            }
        }
    }

    for (int i = 0; i < n0; i++) {
        const bool both = (i < n1);
        // ---- wait K(i) only (V(i) newest in FIFO stays in flight), barrier ----
        if (both) asm volatile("s_waitcnt vmcnt(4)" ::: "memory");
        else      asm volatile("s_waitcnt vmcnt(2)" ::: "memory");
        __builtin_amdgcn_s_barrier();

        const int kt = (s ? n0 : 0) + i;          // this wave's global key tile
        const bool active = (s == 0) || both;
        const bool diag = (kt == qj);
        bf16x8 pfrag[4];

        if (active) {
            #pragma unroll
            for (int mb = 0; mb < 2; mb++) {
                floatx16 sacc = (floatx16)(0.f);
                __builtin_amdgcn_s_setprio(1);
                #pragma unroll
                for (int kk = 0; kk < 4; kk++) {
                    bf16x8 kf = *(const bf16x8*)&SMEM[0][s][32 * mb + l32][((2 * kk + h) ^ xr) * 8];
                    sacc = __builtin_amdgcn_mfma_f32_32x32x16_bf16(kf, qf[kk], sacc, 0, 0, 0);
                }
                __builtin_amdgcn_s_setprio(0);
                float p[16];
                const int kmb = kt * 64 + 32 * mb + 4 * h;
                #pragma unroll
                for (int r = 0; r < 16; r++) {
                    float pv = __builtin_amdgcn_exp2f(sacc[r]);
                    if (diag) {
                        int ki = kmb + (r & 3) + 8 * (r >> 2);
                        if (ki > qw) pv = 0.f;
                    }
                    lsum += pv;
                    p[r] = pv;
                }
                #pragma unroll
                for (int half = 0; half < 2; half++) {
                    union { bf16x8 v; unsigned u[4]; } pk;
                    #pragma unroll
                    for (int i2 = 0; i2 < 4; i2++) {
                        unsigned ulo = __float_as_uint(p[half * 8 + 2 * i2]);
                        unsigned uhi = __float_as_uint(p[half * 8 + 2 * i2 + 1]);
                        pk.u[i2] = (ulo >> 16) | (uhi & 0xffff0000u);
                    }
                    pfrag[2 * mb + half] = pk.v;
                }
            }
        }

        // ---- V(i) landed + all K(i) reads retired -> barrier ----
        asm volatile("s_waitcnt vmcnt(0)" ::: "memory");
        __builtin_amdgcn_s_barrier();

        // ---- issue K(i+1) into the now-free K region (hides under PV) ----
        if (i + 1 < n0) {
            const bool bothn = (i + 1 < n1);
            #pragma unroll
            for (int c = 0; c < 2; c++) {
                int r = 32 * c + srow;
                gll16(kbase + ((size_t)((i + 1) * 64) + r) * 64 + sgr * 8, &SMEM[0][0][r][lg * 8]);
            }
            if (bothn) {
                #pragma unroll
                for (int c = 0; c < 2; c++) {
                    int r = 32 * c + srow;
                    gll16(kbase + ((size_t)((n0 + i + 1) * 64) + r) * 64 + sgr * 8, &SMEM[0][1][r][lg * 8]);
                }
            }
        }

        if (active) {
            __builtin_amdgcn_s_setprio(1);
            #pragma unroll
            for (int mbo = 0; mbo < 2; mbo++) {
                #pragma unroll
                for (int kk = 0; kk < 4; kk++) {
                    bf16x8 vf = *(const bf16x8*)&SMEM[1][s][32 * mbo + l32][((2 * kk + h) ^ xr) * 8];
                    accO[mbo] = __builtin_amdgcn_mfma_f32_32x32x16_bf16(vf, pfrag[kk], accO[mbo], 0, 0, 0);
                }
            }
            __builtin_amdgcn_s_setprio(0);
        }

        // ---- all V(i) reads retired -> barrier, then issue V(i+1) (hides under QK) ----
        __builtin_amdgcn_s_barrier();
        if (i + 1 < n0) {
            const bool bothn = (i + 1 < n1);
            #pragma unroll
            for (int c = 0; c < 2; c++) {
                int r = 32 * c + srow;
                gll16(vbase + (size_t)r * TT + (i + 1) * 64 + sgr * 8, &SMEM[1][0][r][lg * 8]);
            }
            if (bothn) {
                #pragma unroll
                for (int c = 0; c < 2; c++) {
                    int r = 32 * c + srow;
                    gll16(vbase + (size_t)r * TT + (n0 + i + 1) * 64 + sgr * 8, &SMEM[1][1][r][lg * 8]);
                }
            }
        }
    }

    // ---- epilogue: cross-split combine in LDS, normalize, write Yb ----
    lsum += __shfl_xor(lsum, 32);
    __syncthreads();                                    // all LDS tile reads done
    float* Fb = (float*)&SMEM[0][0][0][0];              // 64 rows x 65 floats = 16640 B <= 32 KB
    float* Lb = Fb + 64 * 65;                           // 64 floats
    if (s == 1) {
        float* f = Fb + (size_t)(g * 32 + l32) * 65;    // stride 65: conflict-free
        #pragma unroll
        for (int mbo = 0; mbo < 2; mbo++)
            #pragma unroll
            for (int a = 0; a < 4; a++) {
                int d0 = 32 * mbo + 8 * a + 4 * h;
                f[d0 + 0] = accO[mbo][4 * a + 0];
                f[d0 + 1] = accO[mbo][4 * a + 1];
                f[d0 + 2] = accO[mbo][4 * a + 2];
                f[d0 + 3] = accO[mbo][4 * a + 3];
            }
        if (lane < 32) Lb[g * 32 + l32] = lsum;
    }
    __syncthreads();
    if (s == 0) {
        const float* f = Fb + (size_t)(g * 32 + l32) * 65;
        const float inv = 1.0f / (lsum + Lb[g * 32 + l32]);
        const int bb = bh >> 4, hh = bh & 15;
        unsigned short* orow = Yb + ((size_t)(bb * TT + qw)) * CC + hh * 64;
        #pragma unroll
        for (int mbo = 0; mbo < 2; mbo++)
            #pragma unroll
            for (int a = 0; a < 4; a++) {
                int d0 = 32 * mbo + 8 * a + 4 * h;
                ushort4 o4;
                o4.x = f2bf((accO[mbo][4 * a + 0] + f[d0 + 0]) * inv);
                o4.y = f2bf((accO[mbo][4 * a + 1] + f[d0 + 1]) * inv);
                o4.z = f2bf((accO[mbo][4 * a + 2] + f[d0 + 2]) * inv);
                o4.w = f2bf((accO[mbo][4 * a + 3] + f[d0 + 3]) * inv);
                *(ushort4*)(orow + d0) = o4;
            }
    }
}

extern "C" void kernel_launch(void* const* d_in, const int* in_sizes, int n_in,
                              void* d_out, int out_size, void* d_ws, size_t ws_size,
                              hipStream_t stream) {
    (void)in_sizes; (void)n_in; (void)out_size; (void)ws_size;
    const float* x  = (const float*)d_in[0];
    const float* Wq = (const float*)d_in[1];
    const float* Wk = (const float*)d_in[2];
    const float* Wv = (const float*)d_in[3];
    const float* Wo = (const float*)d_in[4];
    float* out = (float*)d_out;
    char* ws = (char*)d_ws;

    unsigned short* xb    = (unsigned short*)(ws + 0);                      //  8 MB
    unsigned short* wqkvb = (unsigned short*)(ws + (8ull  << 20));          //  6 MB
    unsigned short* wob   = (unsigned short*)(ws + (14ull << 20));          //  2 MB
    unsigned short* Qb    = (unsigned short*)(ws + (16ull << 20));          //  8 MB [BH,T,D] (pre-scaled)
    unsigned short* Kb    = (unsigned short*)(ws + (24ull << 20));          //  8 MB [BH,T,D]
    unsigned short* Vb    = (unsigned short*)(ws + (32ull << 20));          //  8 MB [BH,T,D]
    unsigned short* Vt    = (unsigned short*)(ws + (40ull << 20));          //  8 MB [BH,D,T] slot-permuted
    unsigned short* Yb    = (unsigned short*)(ws + (48ull << 20));          //  8 MB
    float2* tabQ = (float2*)(ws + (73ull << 20));                           // 512 KB
    float2* tabK = (float2*)(ws + (73ull << 20) + (512ull << 10));          // 512 KB

    cast_all_k<<<8448, 256, 0, stream>>>(x, Wq, Wk, Wv, Wo, xb, wqkvb, wob, tabQ, tabK);
    gemm_qkv_k<<<768, 256, 0, stream>>>(xb, wqkvb, tabQ, tabK, Qb, Kb, Vb);
    vtr_k<<<dim3(32, 32), 256, 0, stream>>>(Vb, Vt);
    flash_k<<<1024, 256, 0, stream>>>(Qb, Kb, Vt, Yb);
    gemm_o_k<<<512, 256, 0, stream>>>(Yb, wob, out, 1024, 1024);
}